// Round 1
// baseline (37.176 us; speedup 1.0000x reference)
//
#include <hip/hip_runtime.h>
#include <hip/hip_bf16.h>

#define DD 256
#define M_ROWS 16384

typedef float f32x4 __attribute__((ext_vector_type(4)));
typedef __bf16 bf16x8 __attribute__((ext_vector_type(8)));

// ---------------------------------------------------------------------------
// W_c = Wout @ Wv  (Wv = rows [2D,3D) of Wqkv), stored as bf16 row-major.
// 64 blocks x 256 threads; each block computes 4 rows of W_c.
// ---------------------------------------------------------------------------
__global__ __launch_bounds__(256) void wc_kernel(
    const float* __restrict__ Wqkv, const float* __restrict__ Wout,
    __bf16* __restrict__ Wc) {
  __shared__ float wrow[4][DD];
  const int j = threadIdx.x;
  const int i0 = blockIdx.x * 4;
#pragma unroll
  for (int ri = 0; ri < 4; ++ri) wrow[ri][j] = Wout[(i0 + ri) * DD + j];
  __syncthreads();
  const float* __restrict__ Wv = Wqkv + 2 * DD * DD;
  float acc0 = 0.f, acc1 = 0.f, acc2 = 0.f, acc3 = 0.f;
  for (int d = 0; d < DD; ++d) {
    float wv = Wv[d * DD + j];  // coalesced; wrow[*][d] is broadcast
    acc0 += wrow[0][d] * wv;
    acc1 += wrow[1][d] * wv;
    acc2 += wrow[2][d] * wv;
    acc3 += wrow[3][d] * wv;
  }
  Wc[(size_t)(i0 + 0) * DD + j] = (__bf16)acc0;
  Wc[(size_t)(i0 + 1) * DD + j] = (__bf16)acc1;
  Wc[(size_t)(i0 + 2) * DD + j] = (__bf16)acc2;
  Wc[(size_t)(i0 + 3) * DD + j] = (__bf16)acc3;
}

// ---------------------------------------------------------------------------
// b_c[i] = bout[i] + sum_d Wout[i][d] * bqkv[2D + d].  One block per i.
// ---------------------------------------------------------------------------
__global__ __launch_bounds__(256) void bc_kernel(
    const float* __restrict__ Wout, const float* __restrict__ bqkv,
    const float* __restrict__ bout, float* __restrict__ bc) {
  const int i = blockIdx.x;
  const int t = threadIdx.x;
  float p = Wout[(size_t)i * DD + t] * bqkv[2 * DD + t];
#pragma unroll
  for (int off = 32; off > 0; off >>= 1) p += __shfl_down(p, off);
  __shared__ float red[4];
  if ((t & 63) == 0) red[t >> 6] = p;
  __syncthreads();
  if (t == 0) bc[i] = bout[i] + red[0] + red[1] + red[2] + red[3];
}

// ---------------------------------------------------------------------------
// out = x + x @ Wc^T + bc.
// Both operands k-contiguous row-major -> direct 16B MFMA fragment loads
// (m97 gemm_bt structure). Wave = 32 rows x 64 cols; block = 4 waves
// covering 32 rows x 256 cols; grid = 16384/32 = 512 blocks.
// ---------------------------------------------------------------------------
__global__ __launch_bounds__(256) void knn_attn_main(
    const float* __restrict__ x, const __bf16* __restrict__ Wc,
    const float* __restrict__ bc, float* __restrict__ out) {
  const int t = threadIdx.x;
  const int w = t >> 6;   // wave 0..3 -> column group
  const int l = t & 63;   // lane
  const int r0 = blockIdx.x * 32;
  const int c0 = w * 64;
  const int lr = l & 15;        // row-in-tile for A/B fragments
  const int lk = (l >> 4) * 8;  // k-offset within a 32-wide k-slice

  // A fragments: 2 row-tiles x 8 k-slices, fp32 -> bf16 inline.
  bf16x8 a[2][8];
#pragma unroll
  for (int rt = 0; rt < 2; ++rt) {
    const float* xr = x + (size_t)(r0 + rt * 16 + lr) * DD + lk;
#pragma unroll
    for (int ks = 0; ks < 8; ++ks) {
      f32x4 lo = *(const f32x4*)(xr + ks * 32);
      f32x4 hi = *(const f32x4*)(xr + ks * 32 + 4);
      bf16x8 v;
#pragma unroll
      for (int jj = 0; jj < 4; ++jj) {
        v[jj] = (__bf16)lo[jj];
        v[4 + jj] = (__bf16)hi[jj];
      }
      a[rt][ks] = v;
    }
  }

  f32x4 acc[2][4] = {};

#pragma unroll
  for (int ct = 0; ct < 4; ++ct) {
    const __bf16* wr = Wc + (size_t)(c0 + ct * 16 + lr) * DD + lk;
#pragma unroll
    for (int ks = 0; ks < 8; ++ks) {
      bf16x8 b = *(const bf16x8*)(wr + ks * 32);  // L2-resident, 16B/lane
      acc[0][ct] =
          __builtin_amdgcn_mfma_f32_16x16x32_bf16(a[0][ks], b, acc[0][ct], 0, 0, 0);
      acc[1][ct] =
          __builtin_amdgcn_mfma_f32_16x16x32_bf16(a[1][ks], b, acc[1][ct], 0, 0, 0);
    }
  }

  // Epilogue: C/D layout col = lane&15, row = (lane>>4)*4 + reg (m89/m91).
  const int orow = (l >> 4) * 4;
  const int ocol = l & 15;
#pragma unroll
  for (int ct = 0; ct < 4; ++ct) {
    const int c = c0 + ct * 16 + ocol;
    const float bias = bc[c];
#pragma unroll
    for (int rt = 0; rt < 2; ++rt) {
#pragma unroll
      for (int rg = 0; rg < 4; ++rg) {
        const size_t idx = (size_t)(r0 + rt * 16 + orow + rg) * DD + c;
        out[idx] = acc[rt][ct][rg] + x[idx] + bias;
      }
    }
  }
}

extern "C" void kernel_launch(void* const* d_in, const int* in_sizes, int n_in,
                              void* d_out, int out_size, void* d_ws, size_t ws_size,
                              hipStream_t stream) {
  const float* x = (const float*)d_in[0];
  const float* Wqkv = (const float*)d_in[1];
  const float* bqkv = (const float*)d_in[2];
  const float* Wout = (const float*)d_in[3];
  const float* bout = (const float*)d_in[4];
  float* out = (float*)d_out;

  __bf16* Wc = (__bf16*)d_ws;                                   // 256*256*2 = 128 KiB
  float* bc = (float*)((char*)d_ws + DD * DD * sizeof(__bf16)); // +1 KiB

  wc_kernel<<<DD / 4, 256, 0, stream>>>(Wqkv, Wout, Wc);
  bc_kernel<<<DD, 256, 0, stream>>>(Wout, bqkv, bout, bc);
  knn_attn_main<<<M_ROWS / 32, 256, 0, stream>>>(x, Wc, bc, out);
}